// Round 6
// baseline (141.244 us; speedup 1.0000x reference)
//
#include <hip/hip_runtime.h>

#define THREADS 256

// problem sizes
#define Bsz 2
#define HWp 16384          // 128*128
#define Ntot (Bsz*HWp)     // 32768
#define HID 256
#define Mm 1728
#define FMC 17
#define W_OFF 98304        // 'out' elements precede 'weights' in d_out

// ws layout (in floats)
#define F1_OFF  16384                       // relu(conv1): 2*16*128*128 floats
#define F1_SZ   (Bsz*16*HWp)
#define FM_OFF  (F1_OFF + F1_SZ)            // fm rows: 32768*17 floats
// after k2, the F1 region is dead -> reuse it for bf16 B (1728*256*2 B)

typedef __attribute__((ext_vector_type(8))) short bf16x8;
typedef __attribute__((ext_vector_type(4))) float f32x4;

static __device__ __forceinline__ short f2bf(float x) {
    unsigned u = __builtin_bit_cast(unsigned, x);
    unsigned r = (u + 0x7fff + ((u >> 16) & 1)) >> 16;
    return (short)r;
}

// ---------------- K1: conv1 on upsampled feature + relu ----------------
__global__ __launch_bounds__(THREADS) void k1_conv1(const float* __restrict__ feat,
                                                    const float* __restrict__ w1,
                                                    const float* __restrict__ b1,
                                                    float* __restrict__ f1) {
    __shared__ float sW[4 * 64 * 4];   // [pp][ic][u*2+v]
    int tid = threadIdx.x;
    int t = blockIdx.x * THREADS + tid;
    int c = t & 63, r = (t >> 6) & 63, oc = (t >> 12) & 15, bb = t >> 16;

    #pragma unroll
    for (int q = 0; q < 4; ++q) {
        int e = tid * 4 + q;
        int v = e & 1, u = (e >> 1) & 1, ic = (e >> 2) & 63, pp = (e >> 8) & 3;
        int pi = pp >> 1, pj = pp & 1;
        float s = 0.f;
        for (int ki = 0; ki < 3; ++ki) {
            bool okki = pi ? (u ? (ki == 2) : (ki <= 1)) : (u ? (ki >= 1) : (ki == 0));
            if (!okki) continue;
            for (int kj = 0; kj < 3; ++kj) {
                bool okkj = pj ? (v ? (kj == 2) : (kj <= 1)) : (v ? (kj >= 1) : (kj == 0));
                if (okkj) s += w1[((oc * 64 + ic) * 3 + ki) * 3 + kj];
            }
        }
        sW[(pp * 64 + ic) * 4 + u * 2 + v] = s;
    }
    __syncthreads();

    float bias = b1[oc];
    float acc00 = bias, acc01 = bias, acc10 = bias, acc11 = bias;

    float my0 = (r > 0) ? 1.f : 0.f, my2 = (r < 63) ? 1.f : 0.f;
    float mx0 = (c > 0) ? 1.f : 0.f, mx2 = (c < 63) ? 1.f : 0.f;
    float m00 = my0 * mx0, m01 = my0, m02 = my0 * mx2;
    float m10 = mx0,       m12 = mx2;
    float m20 = my2 * mx0, m21 = my2, m22 = my2 * mx2;
    int ro0 = (r > 0) ? -64 : 0, ro2 = (r < 63) ? 64 : 0;
    int co0 = (c > 0) ? -1 : 0,  co2 = (c < 63) ? 1 : 0;

    const float* fb = feat + bb * 64 * 4096 + r * 64 + c;
    for (int ic = 0; ic < 64; ++ic) {
        const float* p1 = fb + ic * 4096;
        const float* p0 = p1 + ro0;
        const float* p2 = p1 + ro2;
        float v00 = p0[co0] * m00, v01 = p0[0] * m01, v02 = p0[co2] * m02;
        float v10 = p1[co0] * m10, v11 = p1[0],       v12 = p1[co2] * m12;
        float v20 = p2[co0] * m20, v21 = p2[0] * m21, v22 = p2[co2] * m22;

        f32x4 w0 = *(const f32x4*)(sW + (0 * 64 + ic) * 4);
        f32x4 w1v = *(const f32x4*)(sW + (1 * 64 + ic) * 4);
        f32x4 w2v = *(const f32x4*)(sW + (2 * 64 + ic) * 4);
        f32x4 w3 = *(const f32x4*)(sW + (3 * 64 + ic) * 4);

        acc00 = fmaf(w0[0], v00, acc00); acc00 = fmaf(w0[1], v01, acc00);
        acc00 = fmaf(w0[2], v10, acc00); acc00 = fmaf(w0[3], v11, acc00);
        acc01 = fmaf(w1v[0], v01, acc01); acc01 = fmaf(w1v[1], v02, acc01);
        acc01 = fmaf(w1v[2], v11, acc01); acc01 = fmaf(w1v[3], v12, acc01);
        acc10 = fmaf(w2v[0], v10, acc10); acc10 = fmaf(w2v[1], v11, acc10);
        acc10 = fmaf(w2v[2], v20, acc10); acc10 = fmaf(w2v[3], v21, acc10);
        acc11 = fmaf(w3[0], v11, acc11); acc11 = fmaf(w3[1], v12, acc11);
        acc11 = fmaf(w3[2], v21, acc11); acc11 = fmaf(w3[3], v22, acc11);
    }

    float* fo = f1 + (bb * 16 + oc) * HWp + (2 * r) * 128 + 2 * c;
    float2 r0 = make_float2(fmaxf(acc00, 0.f), fmaxf(acc01, 0.f));
    float2 r1 = make_float2(fmaxf(acc10, 0.f), fmaxf(acc11, 0.f));
    *reinterpret_cast<float2*>(fo) = r0;
    *reinterpret_cast<float2*>(fo + 128) = r1;
}

// ---------------- K2: conv2 -> fm rows (ch16 = pos plane 0) ----------------
__global__ __launch_bounds__(THREADS) void k2_conv2_fm(const float* __restrict__ f1,
                                                       const float* __restrict__ w2,
                                                       const float* __restrict__ b2,
                                                       const float* __restrict__ pos,
                                                       float* __restrict__ fm) {
    int t = blockIdx.x * THREADS + threadIdx.x;
    if (t >= Bsz * FMC * HWp) return;
    int J = t & 127, I = (t >> 7) & 127;
    int bc = t >> 14;
    int ch = bc % FMC, bb = bc / FMC;
    int n = bb * HWp + I * 128 + J;
    float val;
    if (ch == 16) {
        val = pos[(I * 128 + J) * 3];
    } else {
        float acc = b2[ch];
        for (int ic = 0; ic < 16; ++ic) {
            const float* fb = f1 + (bb * 16 + ic) * HWp;
            const float* wb = w2 + (ch * 16 + ic) * 9;
            for (int ki = 0; ki < 3; ++ki) {
                int y = I + ki - 1;
                if ((unsigned)y >= 128u) continue;
                const float* row = fb + y * 128;
                for (int kj = 0; kj < 3; ++kj) {
                    int x = J + kj - 1;
                    if ((unsigned)x >= 128u) continue;
                    acc = fmaf(row[x], wb[ki * 3 + kj], acc);
                }
            }
        }
        val = acc;
    }
    fm[n * FMC + ch] = val;
}

// ---------------- K3: f2w2_w (1728x256 fp32) -> bf16 in fragment-major -----
__global__ __launch_bounds__(THREADS) void k3_cvtB(const float* __restrict__ w2g,
                                                   short* __restrict__ wB2) {
    int t = blockIdx.x * THREADS + threadIdx.x;
    int i = t & 7, l = (t >> 3) & 63, ct = (t >> 9) & 3, s = (t >> 11) & 7, mc = t >> 14;
    int col = mc * 64 + ct * 16 + (l & 15);
    int k = s * 32 + (l >> 4) * 8 + i;
    wB2[t] = f2bf(w2g[col * HID + k]);
}

// ---------------- K4: GEMM1(+relu) + bf16-MFMA GEMM2 + fused einsum out ----
// Operand-swapped MFMA: D[row=m][col=pixel]; lane holds pixel=l&15 and 4
// consecutive m (regs) -> dwordx4 weight stores; einsum m-sum is in-lane.
__global__ __launch_bounds__(THREADS, 2) void k4_gemm(const float* __restrict__ fm,
                                                      const float* __restrict__ w1g,
                                                      const float* __restrict__ b1g,
                                                      const short* __restrict__ wB2,
                                                      const float* __restrict__ b2g,
                                                      const float* __restrict__ x0g,
                                                      float* __restrict__ dout) {
    // sA layout (shorts): element (row,k) at ((k>>3)*64 + row)*8 + (k&7)
    __shared__ short    sA[16384];     // 32 KB
    __shared__ float    sFM[64 * 20];  // padded stride 20
    __shared__ int      sOB[64];
    __shared__ float    sX[6528];      // [64ch][3ki][34cols], zero-padded
    __shared__ unsigned sLUT[1792];    // m -> (ch*3+ki)*34 + kj (16B-aligned reads)
    __shared__ float    sOut[4 * 64 * 3];

    int tid = threadIdx.x;
    int n0 = blockIdx.x * 64;
    int bb = n0 >> 14, tt = n0 & 16383, I = tt >> 7, J0 = tt & 127;
    int i0 = I >> 1, jmin = J0 >> 1;

    for (int idx = tid; idx < 64 * FMC; idx += THREADS) {
        int r = idx / FMC, i2 = idx - r * FMC;
        sFM[r * 20 + i2] = fm[n0 * FMC + idx];
    }
    if (tid < 64) {
        int J = J0 + tid;
        int s = ((I & 1) << 1) | (J & 1);
        int p = ((I >> 1) << 6) | (J >> 1);
        sOB[tid] = W_OFF + ((bb * 4 + s) * 4096 + p) * Mm;
    }
    // x0 slab + LUT for fused einsum
    for (int m = tid; m < Mm; m += THREADS) {
        int k = m / 3;
        int ch = k / 9, rem = k - ch * 9;
        int ki = rem / 3, kj = rem - ki * 3;
        sLUT[m] = (unsigned)((ch * 3 + ki) * 34 + kj);
    }
    {
        const float* x0b = x0g + bb * 64 * 4096;
        for (int e = tid; e < 6528; e += THREADS) {
            int ch = e / 102, r2 = e - ch * 102;
            int ki = r2 / 34, jc = r2 - ki * 34;
            int y = i0 + ki - 1, x = jmin + jc - 1;
            float v = 0.f;
            if ((unsigned)y < 64u && (unsigned)x < 64u) v = x0b[(ch * 64 + y) * 64 + x];
            sX[e] = v;
        }
    }
    __syncthreads();

    // GEMM1: thread tid computes hdn[r][k=tid] for all 64 rows -> sA bf16
    {
        float wreg[FMC];
        #pragma unroll
        for (int i = 0; i < FMC; ++i) wreg[i] = w1g[tid * FMC + i];
        float bj = b1g[tid];
        int g = (tid >> 3) & 7;                       // bank-rotation group
        int base = (tid >> 3) * 512 + (tid & 7);      // short index
        for (int rr = 0; rr < 64; ++rr) {
            int r = (rr + g) & 63;
            const float* fr = sFM + r * 20;
            f32x4 x0 = *(const f32x4*)fr;
            f32x4 x1 = *(const f32x4*)(fr + 4);
            f32x4 x2 = *(const f32x4*)(fr + 8);
            f32x4 x3 = *(const f32x4*)(fr + 12);
            float s = fmaf(fr[16], wreg[16], bj);
            s = fmaf(x0[0], wreg[0], s);  s = fmaf(x0[1], wreg[1], s);
            s = fmaf(x0[2], wreg[2], s);  s = fmaf(x0[3], wreg[3], s);
            s = fmaf(x1[0], wreg[4], s);  s = fmaf(x1[1], wreg[5], s);
            s = fmaf(x1[2], wreg[6], s);  s = fmaf(x1[3], wreg[7], s);
            s = fmaf(x2[0], wreg[8], s);  s = fmaf(x2[1], wreg[9], s);
            s = fmaf(x2[2], wreg[10], s); s = fmaf(x2[3], wreg[11], s);
            s = fmaf(x3[0], wreg[12], s); s = fmaf(x3[1], wreg[13], s);
            s = fmaf(x3[2], wreg[14], s); s = fmaf(x3[3], wreg[15], s);
            sA[base + r * 8] = f2bf(fmaxf(s, 0.f));
        }
    }
    __syncthreads();

    int wid = tid >> 6, l = tid & 63;
    int lm = l & 15, lg = l >> 4;
    int lg3 = lg % 3;

    // per-lane pixel bases: pixel = rt*16 + lm
    int pixbase[4], jl[4];
    #pragma unroll
    for (int rt = 0; rt < 4; ++rt) {
        pixbase[rt] = sOB[rt * 16 + lm];
        jl[rt] = rt * 8 + (lm >> 1);       // (rt*16+lm)>>1
    }

    const short* aptr = sA + lg * 512 + lm * 8;

    float racc[4][3];
    #pragma unroll
    for (int rt = 0; rt < 4; ++rt) {
        racc[rt][0] = 0.f; racc[rt][1] = 0.f; racc[rt][2] = 0.f;
    }

    for (int mc = wid; mc < 27; mc += 4) {
        int m0 = mc * 64;
        f32x4 acc[4][4];
        #pragma unroll
        for (int ct = 0; ct < 4; ++ct) {
            f32x4 bias4 = *(const f32x4*)(b2g + m0 + ct * 16 + lg * 4);
            #pragma unroll
            for (int rt = 0; rt < 4; ++rt)
                acc[rt][ct] = bias4;
        }
        // fragment-major B: contiguous 1 KB per (s,ct) load
        const short* bbase = wB2 + (size_t)mc * 16384 + l * 8;
        #pragma unroll 2
        for (int s = 0; s < 8; ++s) {
            bf16x8 af[4], bfr[4];
            #pragma unroll
            for (int rt = 0; rt < 4; ++rt)
                af[rt] = *(const bf16x8*)(aptr + s * 2048 + rt * 128);
            #pragma unroll
            for (int ct = 0; ct < 4; ++ct)
                bfr[ct] = *(const bf16x8*)(bbase + (s * 4 + ct) * 512);
            // swapped operands: rows = weight cols m, cols = pixel rows
            #pragma unroll
            for (int rt = 0; rt < 4; ++rt)
                #pragma unroll
                for (int ct = 0; ct < 4; ++ct)
                    acc[rt][ct] = __builtin_amdgcn_mfma_f32_16x16x32_bf16(
                        bfr[ct], af[rt], acc[rt][ct], 0, 0, 0);
        }
        // store weights: one dwordx4 per (rt,ct), nontemporal
        #pragma unroll
        for (int rt = 0; rt < 4; ++rt)
            #pragma unroll
            for (int ct = 0; ct < 4; ++ct)
                __builtin_nontemporal_store(acc[rt][ct],
                    (f32x4*)(dout + pixbase[rt] + m0 + ct * 16 + lg * 4));
        // fused einsum accumulation (rotated-o: o = (mc+ct+lg+r)%3)
        unsigned lutv[4];
#define ACCUM(QB)                                                              \
        _Pragma("unroll")                                                      \
        for (int ct = 0; ct < 4; ++ct) {                                       \
            *(uint4*)lutv = *(const uint4*)(sLUT + m0 + ct * 16 + lg * 4);     \
            _Pragma("unroll")                                                  \
            for (int r = 0; r < 4; ++r) {                                      \
                _Pragma("unroll")                                              \
                for (int rt = 0; rt < 4; ++rt) {                               \
                    float v = sX[lutv[r] + jl[rt]];                            \
                    racc[rt][((QB) + ct + r) % 3] =                            \
                        fmaf(acc[rt][ct][r], v, racc[rt][((QB) + ct + r) % 3]);\
                }                                                              \
            }                                                                  \
        }
        switch (mc % 3) {
            case 0: ACCUM(0); break;
            case 1: ACCUM(1); break;
            default: ACCUM(2); break;
        }
#undef ACCUM
    }

    // un-rotate (o = (q+lg3)%3), reduce across the 4 lg groups, stash
    #pragma unroll
    for (int rt = 0; rt < 4; ++rt) {
        float q0 = racc[rt][0], q1 = racc[rt][1], q2 = racc[rt][2];
        float a0 = (lg3 == 0) ? q0 : ((lg3 == 1) ? q2 : q1);
        float a1 = (lg3 == 0) ? q1 : ((lg3 == 1) ? q0 : q2);
        float a2 = (lg3 == 0) ? q2 : ((lg3 == 1) ? q1 : q0);
        a0 += __shfl_xor(a0, 16, 64); a0 += __shfl_xor(a0, 32, 64);
        a1 += __shfl_xor(a1, 16, 64); a1 += __shfl_xor(a1, 32, 64);
        a2 += __shfl_xor(a2, 16, 64); a2 += __shfl_xor(a2, 32, 64);
        if (l < 16) {
            float* so = sOut + (wid * 64 + rt * 16 + lm) * 3;
            so[0] = a0; so[1] = a1; so[2] = a2;
        }
    }
    __syncthreads();
    if (tid < 192) {
        float s = sOut[tid] + sOut[192 + tid] + sOut[384 + tid] + sOut[576 + tid];
        int pix = tid / 3, o = tid - 3 * pix;
        __builtin_nontemporal_store(s, dout + bb * 3 * HWp + o * HWp + I * 128 + J0 + pix);
    }
}

extern "C" void kernel_launch(void* const* d_in, const int* in_sizes, int n_in,
                              void* d_out, int out_size, void* d_ws, size_t ws_size,
                              hipStream_t stream) {
    const float* x0      = (const float*)d_in[0];
    const float* feature = (const float*)d_in[1];
    const float* pos     = (const float*)d_in[2];
    const float* w1      = (const float*)d_in[4];
    const float* b1      = (const float*)d_in[5];
    const float* w2      = (const float*)d_in[6];
    const float* b2      = (const float*)d_in[7];
    const float* f2w1_w  = (const float*)d_in[8];
    const float* f2w1_b  = (const float*)d_in[9];
    const float* f2w2_w  = (const float*)d_in[10];
    const float* f2w2_b  = (const float*)d_in[11];

    float* out = (float*)d_out;
    float* ws  = (float*)d_ws;
    float* f1  = ws + F1_OFF;
    float* fm  = ws + FM_OFF;
    short* wB2 = (short*)(ws + F1_OFF);   // reuse F1 region after k2

    k1_conv1<<<(Bsz * 16 * 64 * 64) / THREADS, THREADS, 0, stream>>>(feature, w1, b1, f1);
    k2_conv2_fm<<<(Bsz * FMC * HWp) / THREADS, THREADS, 0, stream>>>(f1, w2, b2, pos, fm);
    k3_cvtB<<<(Mm * HID) / THREADS, THREADS, 0, stream>>>(f2w2_w, wB2);
    k4_gemm<<<Ntot / 64, THREADS, 0, stream>>>(fm, f2w1_w, f2w1_b, wB2, f2w2_b, x0, out);
}

// Round 7
// 130.248 us; speedup vs baseline: 1.0844x; 1.0844x over previous
//
#include <hip/hip_runtime.h>

#define THREADS 256

// problem sizes
#define Bsz 2
#define HWp 16384          // 128*128
#define Ntot (Bsz*HWp)     // 32768
#define HID 256
#define Mm 1728
#define FMC 17
#define W_OFF 98304        // 'out' elements precede 'weights' in d_out

// ws layout (in floats)
#define F1_OFF  16384                       // relu(conv1): 2*16*128*128 floats
#define F1_SZ   (Bsz*16*HWp)
#define FM_OFF  (F1_OFF + F1_SZ)            // fm rows: 32768*17 floats
// after k2, the F1 region is dead -> reuse it for bf16 B (1728*256*2 B)

typedef __attribute__((ext_vector_type(8))) short bf16x8;
typedef __attribute__((ext_vector_type(4))) float f32x4;

static __device__ __forceinline__ short f2bf(float x) {
    unsigned u = __builtin_bit_cast(unsigned, x);
    unsigned r = (u + 0x7fff + ((u >> 16) & 1)) >> 16;
    return (short)r;
}

// ---------------- K1: conv1 on upsampled feature + relu ----------------
__global__ __launch_bounds__(THREADS) void k1_conv1(const float* __restrict__ feat,
                                                    const float* __restrict__ w1,
                                                    const float* __restrict__ b1,
                                                    float* __restrict__ f1) {
    __shared__ float sW[4 * 64 * 4];   // [pp][ic][u*2+v]
    int tid = threadIdx.x;
    int t = blockIdx.x * THREADS + tid;
    int c = t & 63, r = (t >> 6) & 63, oc = (t >> 12) & 15, bb = t >> 16;

    #pragma unroll
    for (int q = 0; q < 4; ++q) {
        int e = tid * 4 + q;
        int v = e & 1, u = (e >> 1) & 1, ic = (e >> 2) & 63, pp = (e >> 8) & 3;
        int pi = pp >> 1, pj = pp & 1;
        float s = 0.f;
        for (int ki = 0; ki < 3; ++ki) {
            bool okki = pi ? (u ? (ki == 2) : (ki <= 1)) : (u ? (ki >= 1) : (ki == 0));
            if (!okki) continue;
            for (int kj = 0; kj < 3; ++kj) {
                bool okkj = pj ? (v ? (kj == 2) : (kj <= 1)) : (v ? (kj >= 1) : (kj == 0));
                if (okkj) s += w1[((oc * 64 + ic) * 3 + ki) * 3 + kj];
            }
        }
        sW[(pp * 64 + ic) * 4 + u * 2 + v] = s;
    }
    __syncthreads();

    float bias = b1[oc];
    float acc00 = bias, acc01 = bias, acc10 = bias, acc11 = bias;

    float my0 = (r > 0) ? 1.f : 0.f, my2 = (r < 63) ? 1.f : 0.f;
    float mx0 = (c > 0) ? 1.f : 0.f, mx2 = (c < 63) ? 1.f : 0.f;
    float m00 = my0 * mx0, m01 = my0, m02 = my0 * mx2;
    float m10 = mx0,       m12 = mx2;
    float m20 = my2 * mx0, m21 = my2, m22 = my2 * mx2;
    int ro0 = (r > 0) ? -64 : 0, ro2 = (r < 63) ? 64 : 0;
    int co0 = (c > 0) ? -1 : 0,  co2 = (c < 63) ? 1 : 0;

    const float* fb = feat + bb * 64 * 4096 + r * 64 + c;
    for (int ic = 0; ic < 64; ++ic) {
        const float* p1 = fb + ic * 4096;
        const float* p0 = p1 + ro0;
        const float* p2 = p1 + ro2;
        float v00 = p0[co0] * m00, v01 = p0[0] * m01, v02 = p0[co2] * m02;
        float v10 = p1[co0] * m10, v11 = p1[0],       v12 = p1[co2] * m12;
        float v20 = p2[co0] * m20, v21 = p2[0] * m21, v22 = p2[co2] * m22;

        f32x4 w0 = *(const f32x4*)(sW + (0 * 64 + ic) * 4);
        f32x4 w1v = *(const f32x4*)(sW + (1 * 64 + ic) * 4);
        f32x4 w2v = *(const f32x4*)(sW + (2 * 64 + ic) * 4);
        f32x4 w3 = *(const f32x4*)(sW + (3 * 64 + ic) * 4);

        acc00 = fmaf(w0[0], v00, acc00); acc00 = fmaf(w0[1], v01, acc00);
        acc00 = fmaf(w0[2], v10, acc00); acc00 = fmaf(w0[3], v11, acc00);
        acc01 = fmaf(w1v[0], v01, acc01); acc01 = fmaf(w1v[1], v02, acc01);
        acc01 = fmaf(w1v[2], v11, acc01); acc01 = fmaf(w1v[3], v12, acc01);
        acc10 = fmaf(w2v[0], v10, acc10); acc10 = fmaf(w2v[1], v11, acc10);
        acc10 = fmaf(w2v[2], v20, acc10); acc10 = fmaf(w2v[3], v21, acc10);
        acc11 = fmaf(w3[0], v11, acc11); acc11 = fmaf(w3[1], v12, acc11);
        acc11 = fmaf(w3[2], v21, acc11); acc11 = fmaf(w3[3], v22, acc11);
    }

    float* fo = f1 + (bb * 16 + oc) * HWp + (2 * r) * 128 + 2 * c;
    float2 r0 = make_float2(fmaxf(acc00, 0.f), fmaxf(acc01, 0.f));
    float2 r1 = make_float2(fmaxf(acc10, 0.f), fmaxf(acc11, 0.f));
    *reinterpret_cast<float2*>(fo) = r0;
    *reinterpret_cast<float2*>(fo + 128) = r1;
}

// ---------------- K2: conv2 -> fm rows (ch16 = pos plane 0) ----------------
__global__ __launch_bounds__(THREADS) void k2_conv2_fm(const float* __restrict__ f1,
                                                       const float* __restrict__ w2,
                                                       const float* __restrict__ b2,
                                                       const float* __restrict__ pos,
                                                       float* __restrict__ fm) {
    int t = blockIdx.x * THREADS + threadIdx.x;
    if (t >= Bsz * FMC * HWp) return;
    int J = t & 127, I = (t >> 7) & 127;
    int bc = t >> 14;
    int ch = bc % FMC, bb = bc / FMC;
    int n = bb * HWp + I * 128 + J;
    float val;
    if (ch == 16) {
        val = pos[(I * 128 + J) * 3];
    } else {
        float acc = b2[ch];
        for (int ic = 0; ic < 16; ++ic) {
            const float* fb = f1 + (bb * 16 + ic) * HWp;
            const float* wb = w2 + (ch * 16 + ic) * 9;
            for (int ki = 0; ki < 3; ++ki) {
                int y = I + ki - 1;
                if ((unsigned)y >= 128u) continue;
                const float* row = fb + y * 128;
                for (int kj = 0; kj < 3; ++kj) {
                    int x = J + kj - 1;
                    if ((unsigned)x >= 128u) continue;
                    acc = fmaf(row[x], wb[ki * 3 + kj], acc);
                }
            }
        }
        val = acc;
    }
    fm[n * FMC + ch] = val;
}

// ---------------- K3: f2w2_w (1728x256 fp32) -> bf16 in fragment-major -----
__global__ __launch_bounds__(THREADS) void k3_cvtB(const float* __restrict__ w2g,
                                                   short* __restrict__ wB2) {
    int t = blockIdx.x * THREADS + threadIdx.x;
    int i = t & 7, l = (t >> 3) & 63, ct = (t >> 9) & 3, s = (t >> 11) & 7, mc = t >> 14;
    int col = mc * 64 + ct * 16 + (l & 15);
    int k = s * 32 + (l >> 4) * 8 + i;
    wB2[t] = f2bf(w2g[col * HID + k]);
}

// ---------------- K4: GEMM1(+relu) + bf16-MFMA GEMM2 + fused einsum out ----
// Operand-swapped MFMA: D[row=m][col=pixel]; lane holds pixel=l&15 and 4
// consecutive m (regs) -> dwordx4 weight stores; einsum m-sum is in-lane.
// Plain cached stores (NT regressed -14us in R6: 64B segments need L2 merge).
__global__ __launch_bounds__(THREADS, 2) void k4_gemm(const float* __restrict__ fm,
                                                      const float* __restrict__ w1g,
                                                      const float* __restrict__ b1g,
                                                      const short* __restrict__ wB2,
                                                      const float* __restrict__ b2g,
                                                      const float* __restrict__ x0g,
                                                      float* __restrict__ dout) {
    // sA layout (shorts): element (row,k) at ((k>>3)*64 + row)*8 + (k&7)
    __shared__ short    sA[16384];     // 32 KB
    __shared__ float    sFM[64 * 20];  // padded stride 20
    __shared__ int      sOB[64];
    __shared__ float    sX[6528];      // [64ch][3ki][34cols], zero-padded
    __shared__ unsigned sLUT[1792];    // m -> (ch*3+ki)*34 + kj (16B-aligned reads)
    __shared__ float    sOut[4 * 64 * 3];

    int tid = threadIdx.x;
    int n0 = blockIdx.x * 64;
    int bb = n0 >> 14, tt = n0 & 16383, I = tt >> 7, J0 = tt & 127;
    int i0 = I >> 1, jmin = J0 >> 1;

    for (int idx = tid; idx < 64 * FMC; idx += THREADS) {
        int r = idx / FMC, i2 = idx - r * FMC;
        sFM[r * 20 + i2] = fm[n0 * FMC + idx];
    }
    if (tid < 64) {
        int J = J0 + tid;
        int s = ((I & 1) << 1) | (J & 1);
        int p = ((I >> 1) << 6) | (J >> 1);
        sOB[tid] = W_OFF + ((bb * 4 + s) * 4096 + p) * Mm;
    }
    // x0 slab + LUT for fused einsum
    for (int m = tid; m < Mm; m += THREADS) {
        int k = m / 3;
        int ch = k / 9, rem = k - ch * 9;
        int ki = rem / 3, kj = rem - ki * 3;
        sLUT[m] = (unsigned)((ch * 3 + ki) * 34 + kj);
    }
    {
        const float* x0b = x0g + bb * 64 * 4096;
        for (int e = tid; e < 6528; e += THREADS) {
            int ch = e / 102, r2 = e - ch * 102;
            int ki = r2 / 34, jc = r2 - ki * 34;
            int y = i0 + ki - 1, x = jmin + jc - 1;
            float v = 0.f;
            if ((unsigned)y < 64u && (unsigned)x < 64u) v = x0b[(ch * 64 + y) * 64 + x];
            sX[e] = v;
        }
    }
    __syncthreads();

    // GEMM1: thread tid computes hdn[r][k=tid] for all 64 rows -> sA bf16
    {
        float wreg[FMC];
        #pragma unroll
        for (int i = 0; i < FMC; ++i) wreg[i] = w1g[tid * FMC + i];
        float bj = b1g[tid];
        int g = (tid >> 3) & 7;                       // bank-rotation group
        int base = (tid >> 3) * 512 + (tid & 7);      // short index
        for (int rr = 0; rr < 64; ++rr) {
            int r = (rr + g) & 63;
            const float* fr = sFM + r * 20;
            f32x4 x0 = *(const f32x4*)fr;
            f32x4 x1 = *(const f32x4*)(fr + 4);
            f32x4 x2 = *(const f32x4*)(fr + 8);
            f32x4 x3 = *(const f32x4*)(fr + 12);
            float s = fmaf(fr[16], wreg[16], bj);
            s = fmaf(x0[0], wreg[0], s);  s = fmaf(x0[1], wreg[1], s);
            s = fmaf(x0[2], wreg[2], s);  s = fmaf(x0[3], wreg[3], s);
            s = fmaf(x1[0], wreg[4], s);  s = fmaf(x1[1], wreg[5], s);
            s = fmaf(x1[2], wreg[6], s);  s = fmaf(x1[3], wreg[7], s);
            s = fmaf(x2[0], wreg[8], s);  s = fmaf(x2[1], wreg[9], s);
            s = fmaf(x2[2], wreg[10], s); s = fmaf(x2[3], wreg[11], s);
            s = fmaf(x3[0], wreg[12], s); s = fmaf(x3[1], wreg[13], s);
            s = fmaf(x3[2], wreg[14], s); s = fmaf(x3[3], wreg[15], s);
            sA[base + r * 8] = f2bf(fmaxf(s, 0.f));
        }
    }
    __syncthreads();

    int wid = tid >> 6, l = tid & 63;
    int lm = l & 15, lg = l >> 4;
    int lg3 = lg % 3;

    // per-lane pixel bases: pixel = rt*16 + lm
    int pixbase[4], jl[4];
    #pragma unroll
    for (int rt = 0; rt < 4; ++rt) {
        pixbase[rt] = sOB[rt * 16 + lm];
        jl[rt] = rt * 8 + (lm >> 1);       // (rt*16+lm)>>1
    }

    const short* aptr = sA + lg * 512 + lm * 8;

    float racc[4][3];
    #pragma unroll
    for (int rt = 0; rt < 4; ++rt) {
        racc[rt][0] = 0.f; racc[rt][1] = 0.f; racc[rt][2] = 0.f;
    }

    for (int mc = wid; mc < 27; mc += 4) {
        int m0 = mc * 64;
        f32x4 acc[4][4];
        #pragma unroll
        for (int ct = 0; ct < 4; ++ct) {
            f32x4 bias4 = *(const f32x4*)(b2g + m0 + ct * 16 + lg * 4);
            #pragma unroll
            for (int rt = 0; rt < 4; ++rt)
                acc[rt][ct] = bias4;
        }
        // fragment-major B: contiguous 1 KB per (s,ct) load
        const short* bbase = wB2 + (size_t)mc * 16384 + l * 8;
        #pragma unroll 2
        for (int s = 0; s < 8; ++s) {
            bf16x8 af[4], bfr[4];
            #pragma unroll
            for (int rt = 0; rt < 4; ++rt)
                af[rt] = *(const bf16x8*)(aptr + s * 2048 + rt * 128);
            #pragma unroll
            for (int ct = 0; ct < 4; ++ct)
                bfr[ct] = *(const bf16x8*)(bbase + (s * 4 + ct) * 512);
            // swapped operands: rows = weight cols m, cols = pixel rows
            #pragma unroll
            for (int rt = 0; rt < 4; ++rt)
                #pragma unroll
                for (int ct = 0; ct < 4; ++ct)
                    acc[rt][ct] = __builtin_amdgcn_mfma_f32_16x16x32_bf16(
                        bfr[ct], af[rt], acc[rt][ct], 0, 0, 0);
        }
        // store weights: one dwordx4 per (rt,ct), plain cached store
        #pragma unroll
        for (int rt = 0; rt < 4; ++rt)
            #pragma unroll
            for (int ct = 0; ct < 4; ++ct)
                *(f32x4*)(dout + pixbase[rt] + m0 + ct * 16 + lg * 4) = acc[rt][ct];
        // fused einsum accumulation (rotated-o: o = (mc+ct+lg+r)%3)
        unsigned lutv[4];
#define ACCUM(QB)                                                              \
        _Pragma("unroll")                                                      \
        for (int ct = 0; ct < 4; ++ct) {                                       \
            *(uint4*)lutv = *(const uint4*)(sLUT + m0 + ct * 16 + lg * 4);     \
            _Pragma("unroll")                                                  \
            for (int r = 0; r < 4; ++r) {                                      \
                _Pragma("unroll")                                              \
                for (int rt = 0; rt < 4; ++rt) {                               \
                    float v = sX[lutv[r] + jl[rt]];                            \
                    racc[rt][((QB) + ct + r) % 3] =                            \
                        fmaf(acc[rt][ct][r], v, racc[rt][((QB) + ct + r) % 3]);\
                }                                                              \
            }                                                                  \
        }
        switch (mc % 3) {
            case 0: ACCUM(0); break;
            case 1: ACCUM(1); break;
            default: ACCUM(2); break;
        }
#undef ACCUM
    }

    // un-rotate (o = (q+lg3)%3), reduce across the 4 lg groups, stash
    #pragma unroll
    for (int rt = 0; rt < 4; ++rt) {
        float q0 = racc[rt][0], q1 = racc[rt][1], q2 = racc[rt][2];
        float a0 = (lg3 == 0) ? q0 : ((lg3 == 1) ? q2 : q1);
        float a1 = (lg3 == 0) ? q1 : ((lg3 == 1) ? q0 : q2);
        float a2 = (lg3 == 0) ? q2 : ((lg3 == 1) ? q1 : q0);
        a0 += __shfl_xor(a0, 16, 64); a0 += __shfl_xor(a0, 32, 64);
        a1 += __shfl_xor(a1, 16, 64); a1 += __shfl_xor(a1, 32, 64);
        a2 += __shfl_xor(a2, 16, 64); a2 += __shfl_xor(a2, 32, 64);
        if (l < 16) {
            float* so = sOut + (wid * 64 + rt * 16 + lm) * 3;
            so[0] = a0; so[1] = a1; so[2] = a2;
        }
    }
    __syncthreads();
    if (tid < 192) {
        float s = sOut[tid] + sOut[192 + tid] + sOut[384 + tid] + sOut[576 + tid];
        int pix = tid / 3, o = tid - 3 * pix;
        dout[bb * 3 * HWp + o * HWp + I * 128 + J0 + pix] = s;
    }
}

extern "C" void kernel_launch(void* const* d_in, const int* in_sizes, int n_in,
                              void* d_out, int out_size, void* d_ws, size_t ws_size,
                              hipStream_t stream) {
    const float* x0      = (const float*)d_in[0];
    const float* feature = (const float*)d_in[1];
    const float* pos     = (const float*)d_in[2];
    const float* w1      = (const float*)d_in[4];
    const float* b1      = (const float*)d_in[5];
    const float* w2      = (const float*)d_in[6];
    const float* b2      = (const float*)d_in[7];
    const float* f2w1_w  = (const float*)d_in[8];
    const float* f2w1_b  = (const float*)d_in[9];
    const float* f2w2_w  = (const float*)d_in[10];
    const float* f2w2_b  = (const float*)d_in[11];

    float* out = (float*)d_out;
    float* ws  = (float*)d_ws;
    float* f1  = ws + F1_OFF;
    float* fm  = ws + FM_OFF;
    short* wB2 = (short*)(ws + F1_OFF);   // reuse F1 region after k2

    k1_conv1<<<(Bsz * 16 * 64 * 64) / THREADS, THREADS, 0, stream>>>(feature, w1, b1, f1);
    k2_conv2_fm<<<(Bsz * FMC * HWp) / THREADS, THREADS, 0, stream>>>(f1, w2, b2, pos, fm);
    k3_cvtB<<<(Mm * HID) / THREADS, THREADS, 0, stream>>>(f2w2_w, wB2);
    k4_gemm<<<Ntot / 64, THREADS, 0, stream>>>(fm, f2w1_w, f2w1_b, wB2, f2w2_b, x0, out);
}

// Round 8
// 123.778 us; speedup vs baseline: 1.1411x; 1.0523x over previous
//
#include <hip/hip_runtime.h>

#define THREADS 256

// problem sizes
#define Bsz 2
#define HWp 16384          // 128*128
#define Ntot (Bsz*HWp)     // 32768
#define HID 256
#define Mm 1728
#define FMC 17
#define W_OFF 98304        // 'out' elements precede 'weights' in d_out

// ws layout (in floats)
#define F1_OFF  0
#define F1_SZ   (Bsz*16*HWp)                 // 524288
#define FM_OFF  F1_SZ                        // 32768*17 = 557056
#define WB2_OFF (FM_OFF + Ntot*FMC)          // bf16 B, 442368 shorts = 221184 floats

typedef __attribute__((ext_vector_type(8))) short bf16x8;
typedef __attribute__((ext_vector_type(4))) float f32x4;

static __device__ __forceinline__ short f2bf(float x) {
    unsigned u = __builtin_bit_cast(unsigned, x);
    unsigned r = (u + 0x7fff + ((u >> 16) & 1)) >> 16;
    return (short)r;
}

// ---------- K13: conv1 (2 src pixels/thread, 1 oc/block) + k3 cvt blocks ----
__global__ __launch_bounds__(THREADS) void k13_conv1_cvt(const float* __restrict__ feat,
                                                         const float* __restrict__ w1,
                                                         const float* __restrict__ b1,
                                                         float* __restrict__ f1,
                                                         const float* __restrict__ w2g,
                                                         short* __restrict__ wB2) {
    int tid = threadIdx.x;
    if (blockIdx.x >= 256) {
        // k3 path: f2w2_w (1728x256 fp32) -> bf16 fragment-major
        int t = (blockIdx.x - 256) * THREADS + tid;
        int i = t & 7, l = (t >> 3) & 63, ct = (t >> 9) & 3, s = (t >> 11) & 7, mc = t >> 14;
        int col = mc * 64 + ct * 16 + (l & 15);
        int k = s * 32 + (l >> 4) * 8 + i;
        wB2[t] = f2bf(w2g[col * HID + k]);
        return;
    }
    __shared__ float sW[4 * 64 * 4];   // [pp][ic][u*2+v] for this block's oc
    int b = blockIdx.x;
    int rb = b & 7, oc = (b >> 3) & 15, bb = b >> 7;
    int c = tid & 63, sr = tid >> 6;
    int r0 = rb * 4 + sr;              // 0..31
    int r1 = r0 + 32;                  // 32..63

    // build weff slice for this oc (1024 entries, 4 per thread)
    #pragma unroll
    for (int q = 0; q < 4; ++q) {
        int e = tid * 4 + q;
        int v = e & 1, u = (e >> 1) & 1, ic = (e >> 2) & 63, pp = (e >> 8) & 3;
        int pi = pp >> 1, pj = pp & 1;
        float s = 0.f;
        for (int ki = 0; ki < 3; ++ki) {
            bool okki = pi ? (u ? (ki == 2) : (ki <= 1)) : (u ? (ki >= 1) : (ki == 0));
            if (!okki) continue;
            for (int kj = 0; kj < 3; ++kj) {
                bool okkj = pj ? (v ? (kj == 2) : (kj <= 1)) : (v ? (kj >= 1) : (kj == 0));
                if (okkj) s += w1[((oc * 64 + ic) * 3 + ki) * 3 + kj];
            }
        }
        sW[(pp * 64 + ic) * 4 + u * 2 + v] = s;
    }
    __syncthreads();

    float bias = b1[oc];
    float aA00 = bias, aA01 = bias, aA10 = bias, aA11 = bias;
    float aB00 = bias, aB01 = bias, aB10 = bias, aB11 = bias;

    float mA = (r0 > 0) ? 1.f : 0.f;   // pixel A top-row mask (bottom always ok)
    float mB = (r1 < 63) ? 1.f : 0.f;  // pixel B bottom-row mask (top always ok)
    float mc0 = (c > 0) ? 1.f : 0.f, mc2 = (c < 63) ? 1.f : 0.f;
    int roA0 = (r0 > 0) ? -64 : 0;
    int roB2 = (r1 < 63) ? 64 : 0;
    int co0 = (c > 0) ? -1 : 0, co2 = (c < 63) ? 1 : 0;

    const float* fbA = feat + bb * 64 * 4096 + r0 * 64 + c;
    const float* fbB = feat + bb * 64 * 4096 + r1 * 64 + c;
    for (int ic = 0; ic < 64; ++ic) {
        const float* pA1 = fbA + ic * 4096;
        const float* pA0 = pA1 + roA0;
        const float* pA2 = pA1 + 64;
        const float* pB1 = fbB + ic * 4096;
        const float* pB0 = pB1 - 64;
        const float* pB2 = pB1 + roB2;

        float vA00 = pA0[co0] * (mA * mc0), vA01 = pA0[0] * mA, vA02 = pA0[co2] * (mA * mc2);
        float vA10 = pA1[co0] * mc0,        vA11 = pA1[0],      vA12 = pA1[co2] * mc2;
        float vA20 = pA2[co0] * mc0,        vA21 = pA2[0],      vA22 = pA2[co2] * mc2;
        float vB00 = pB0[co0] * mc0,        vB01 = pB0[0],      vB02 = pB0[co2] * mc2;
        float vB10 = pB1[co0] * mc0,        vB11 = pB1[0],      vB12 = pB1[co2] * mc2;
        float vB20 = pB2[co0] * (mB * mc0), vB21 = pB2[0] * mB, vB22 = pB2[co2] * (mB * mc2);

        f32x4 w0 = *(const f32x4*)(sW + (0 * 64 + ic) * 4);
        f32x4 w1v = *(const f32x4*)(sW + (1 * 64 + ic) * 4);
        f32x4 w2v = *(const f32x4*)(sW + (2 * 64 + ic) * 4);
        f32x4 w3 = *(const f32x4*)(sW + (3 * 64 + ic) * 4);

        aA00 = fmaf(w0[0], vA00, aA00); aA00 = fmaf(w0[1], vA01, aA00);
        aA00 = fmaf(w0[2], vA10, aA00); aA00 = fmaf(w0[3], vA11, aA00);
        aA01 = fmaf(w1v[0], vA01, aA01); aA01 = fmaf(w1v[1], vA02, aA01);
        aA01 = fmaf(w1v[2], vA11, aA01); aA01 = fmaf(w1v[3], vA12, aA01);
        aA10 = fmaf(w2v[0], vA10, aA10); aA10 = fmaf(w2v[1], vA11, aA10);
        aA10 = fmaf(w2v[2], vA20, aA10); aA10 = fmaf(w2v[3], vA21, aA10);
        aA11 = fmaf(w3[0], vA11, aA11); aA11 = fmaf(w3[1], vA12, aA11);
        aA11 = fmaf(w3[2], vA21, aA11); aA11 = fmaf(w3[3], vA22, aA11);

        aB00 = fmaf(w0[0], vB00, aB00); aB00 = fmaf(w0[1], vB01, aB00);
        aB00 = fmaf(w0[2], vB10, aB00); aB00 = fmaf(w0[3], vB11, aB00);
        aB01 = fmaf(w1v[0], vB01, aB01); aB01 = fmaf(w1v[1], vB02, aB01);
        aB01 = fmaf(w1v[2], vB11, aB01); aB01 = fmaf(w1v[3], vB12, aB01);
        aB10 = fmaf(w2v[0], vB10, aB10); aB10 = fmaf(w2v[1], vB11, aB10);
        aB10 = fmaf(w2v[2], vB20, aB10); aB10 = fmaf(w2v[3], vB21, aB10);
        aB11 = fmaf(w3[0], vB11, aB11); aB11 = fmaf(w3[1], vB12, aB11);
        aB11 = fmaf(w3[2], vB21, aB11); aB11 = fmaf(w3[3], vB22, aB11);
    }

    float* foA = f1 + (bb * 16 + oc) * HWp + (2 * r0) * 128 + 2 * c;
    *reinterpret_cast<float2*>(foA)       = make_float2(fmaxf(aA00, 0.f), fmaxf(aA01, 0.f));
    *reinterpret_cast<float2*>(foA + 128) = make_float2(fmaxf(aA10, 0.f), fmaxf(aA11, 0.f));
    float* foB = f1 + (bb * 16 + oc) * HWp + (2 * r1) * 128 + 2 * c;
    *reinterpret_cast<float2*>(foB)       = make_float2(fmaxf(aB00, 0.f), fmaxf(aB01, 0.f));
    *reinterpret_cast<float2*>(foB + 128) = make_float2(fmaxf(aB10, 0.f), fmaxf(aB11, 0.f));
}

// ---------- K2: conv2 -> fm rows; 8 oc per thread, uniform w2 reads ----------
__global__ __launch_bounds__(THREADS) void k2_conv2_fm(const float* __restrict__ f1,
                                                       const float* __restrict__ w2,
                                                       const float* __restrict__ b2,
                                                       const float* __restrict__ pos,
                                                       float* __restrict__ fm) {
    int tid = threadIdx.x;
    int t = blockIdx.x * THREADS + tid;
    int J = t & 127, I = (t >> 7) & 127, h = (t >> 14) & 1, bb = t >> 15;

    float acc[8];
    #pragma unroll
    for (int o = 0; o < 8; ++o) acc[o] = b2[h * 8 + o];

    int ro0 = (I > 0) ? -128 : 0, ro2 = (I < 127) ? 128 : 0;
    int co0 = (J > 0) ? -1 : 0, co2 = (J < 127) ? 1 : 0;
    float mr0 = (I > 0) ? 1.f : 0.f, mr2 = (I < 127) ? 1.f : 0.f;
    float mcl = (J > 0) ? 1.f : 0.f, mcr = (J < 127) ? 1.f : 0.f;

    const float* fb = f1 + bb * 16 * HWp + I * 128 + J;
    #pragma unroll 4
    for (int ic = 0; ic < 16; ++ic) {
        const float* p1 = fb + ic * HWp;
        const float* p0 = p1 + ro0;
        const float* p2 = p1 + ro2;
        float v0 = p0[co0] * (mr0 * mcl), v1 = p0[0] * mr0, v2 = p0[co2] * (mr0 * mcr);
        float v3 = p1[co0] * mcl,         v4 = p1[0],       v5 = p1[co2] * mcr;
        float v6 = p2[co0] * (mr2 * mcl), v7 = p2[0] * mr2, v8 = p2[co2] * (mr2 * mcr);
        const float* wp = w2 + (h * 8 * 16 + ic) * 9;   // uniform (scalarizable)
        #pragma unroll
        for (int o = 0; o < 8; ++o) {
            const float* w = wp + o * 144;              // (oc*16+ic)*9
            acc[o] = fmaf(v0, w[0], acc[o]); acc[o] = fmaf(v1, w[1], acc[o]);
            acc[o] = fmaf(v2, w[2], acc[o]); acc[o] = fmaf(v3, w[3], acc[o]);
            acc[o] = fmaf(v4, w[4], acc[o]); acc[o] = fmaf(v5, w[5], acc[o]);
            acc[o] = fmaf(v6, w[6], acc[o]); acc[o] = fmaf(v7, w[7], acc[o]);
            acc[o] = fmaf(v8, w[8], acc[o]);
        }
    }
    int n = bb * HWp + I * 128 + J;
    #pragma unroll
    for (int o = 0; o < 8; ++o) fm[n * FMC + h * 8 + o] = acc[o];
    if (h == 0) fm[n * FMC + 16] = pos[(I * 128 + J) * 3];
}

// ---------------- K4: GEMM1(+relu) + bf16-MFMA GEMM2 + fused einsum out ----
// Operand-swapped MFMA: D[row=m][col=pixel]; lane holds pixel=l&15 and 4
// consecutive m (regs) -> dwordx4 weight stores; einsum m-sum is in-lane.
// Plain cached stores (NT regressed -14us in R6: 64B segments need L2 merge).
__global__ __launch_bounds__(THREADS, 2) void k4_gemm(const float* __restrict__ fm,
                                                      const float* __restrict__ w1g,
                                                      const float* __restrict__ b1g,
                                                      const short* __restrict__ wB2,
                                                      const float* __restrict__ b2g,
                                                      const float* __restrict__ x0g,
                                                      float* __restrict__ dout) {
    // sA layout (shorts): element (row,k) at ((k>>3)*64 + row)*8 + (k&7)
    __shared__ short    sA[16384];     // 32 KB
    __shared__ float    sFM[64 * 20];  // padded stride 20
    __shared__ int      sOB[64];
    __shared__ float    sX[6528];      // [64ch][3ki][34cols], zero-padded
    __shared__ unsigned sLUT[1792];    // m -> (ch*3+ki)*34 + kj (16B-aligned reads)
    __shared__ float    sOut[4 * 64 * 3];

    int tid = threadIdx.x;
    int n0 = blockIdx.x * 64;
    int bb = n0 >> 14, tt = n0 & 16383, I = tt >> 7, J0 = tt & 127;
    int i0 = I >> 1, jmin = J0 >> 1;

    for (int idx = tid; idx < 64 * FMC; idx += THREADS) {
        int r = idx / FMC, i2 = idx - r * FMC;
        sFM[r * 20 + i2] = fm[n0 * FMC + idx];
    }
    if (tid < 64) {
        int J = J0 + tid;
        int s = ((I & 1) << 1) | (J & 1);
        int p = ((I >> 1) << 6) | (J >> 1);
        sOB[tid] = W_OFF + ((bb * 4 + s) * 4096 + p) * Mm;
    }
    // x0 slab + LUT for fused einsum
    for (int m = tid; m < Mm; m += THREADS) {
        int k = m / 3;
        int ch = k / 9, rem = k - ch * 9;
        int ki = rem / 3, kj = rem - ki * 3;
        sLUT[m] = (unsigned)((ch * 3 + ki) * 34 + kj);
    }
    {
        const float* x0b = x0g + bb * 64 * 4096;
        for (int e = tid; e < 6528; e += THREADS) {
            int ch = e / 102, r2 = e - ch * 102;
            int ki = r2 / 34, jc = r2 - ki * 34;
            int y = i0 + ki - 1, x = jmin + jc - 1;
            float v = 0.f;
            if ((unsigned)y < 64u && (unsigned)x < 64u) v = x0b[(ch * 64 + y) * 64 + x];
            sX[e] = v;
        }
    }
    __syncthreads();

    // GEMM1: thread tid computes hdn[r][k=tid] for all 64 rows -> sA bf16
    {
        float wreg[FMC];
        #pragma unroll
        for (int i = 0; i < FMC; ++i) wreg[i] = w1g[tid * FMC + i];
        float bj = b1g[tid];
        int g = (tid >> 3) & 7;                       // bank-rotation group
        int base = (tid >> 3) * 512 + (tid & 7);      // short index
        for (int rr = 0; rr < 64; ++rr) {
            int r = (rr + g) & 63;
            const float* fr = sFM + r * 20;
            f32x4 x0 = *(const f32x4*)fr;
            f32x4 x1 = *(const f32x4*)(fr + 4);
            f32x4 x2 = *(const f32x4*)(fr + 8);
            f32x4 x3 = *(const f32x4*)(fr + 12);
            float s = fmaf(fr[16], wreg[16], bj);
            s = fmaf(x0[0], wreg[0], s);  s = fmaf(x0[1], wreg[1], s);
            s = fmaf(x0[2], wreg[2], s);  s = fmaf(x0[3], wreg[3], s);
            s = fmaf(x1[0], wreg[4], s);  s = fmaf(x1[1], wreg[5], s);
            s = fmaf(x1[2], wreg[6], s);  s = fmaf(x1[3], wreg[7], s);
            s = fmaf(x2[0], wreg[8], s);  s = fmaf(x2[1], wreg[9], s);
            s = fmaf(x2[2], wreg[10], s); s = fmaf(x2[3], wreg[11], s);
            s = fmaf(x3[0], wreg[12], s); s = fmaf(x3[1], wreg[13], s);
            s = fmaf(x3[2], wreg[14], s); s = fmaf(x3[3], wreg[15], s);
            sA[base + r * 8] = f2bf(fmaxf(s, 0.f));
        }
    }
    __syncthreads();

    int wid = tid >> 6, l = tid & 63;
    int lm = l & 15, lg = l >> 4;
    int lg3 = lg % 3;

    // per-lane pixel bases: pixel = rt*16 + lm
    int pixbase[4], jl[4];
    #pragma unroll
    for (int rt = 0; rt < 4; ++rt) {
        pixbase[rt] = sOB[rt * 16 + lm];
        jl[rt] = rt * 8 + (lm >> 1);       // (rt*16+lm)>>1
    }

    const short* aptr = sA + lg * 512 + lm * 8;

    float racc[4][3];
    #pragma unroll
    for (int rt = 0; rt < 4; ++rt) {
        racc[rt][0] = 0.f; racc[rt][1] = 0.f; racc[rt][2] = 0.f;
    }

    for (int mc = wid; mc < 27; mc += 4) {
        int m0 = mc * 64;
        f32x4 acc[4][4];
        #pragma unroll
        for (int ct = 0; ct < 4; ++ct) {
            f32x4 bias4 = *(const f32x4*)(b2g + m0 + ct * 16 + lg * 4);
            #pragma unroll
            for (int rt = 0; rt < 4; ++rt)
                acc[rt][ct] = bias4;
        }
        // fragment-major B: contiguous 1 KB per (s,ct) load
        const short* bbase = wB2 + (size_t)mc * 16384 + l * 8;
        #pragma unroll 2
        for (int s = 0; s < 8; ++s) {
            bf16x8 af[4], bfr[4];
            #pragma unroll
            for (int rt = 0; rt < 4; ++rt)
                af[rt] = *(const bf16x8*)(aptr + s * 2048 + rt * 128);
            #pragma unroll
            for (int ct = 0; ct < 4; ++ct)
                bfr[ct] = *(const bf16x8*)(bbase + (s * 4 + ct) * 512);
            // swapped operands: rows = weight cols m, cols = pixel rows
            #pragma unroll
            for (int rt = 0; rt < 4; ++rt)
                #pragma unroll
                for (int ct = 0; ct < 4; ++ct)
                    acc[rt][ct] = __builtin_amdgcn_mfma_f32_16x16x32_bf16(
                        bfr[ct], af[rt], acc[rt][ct], 0, 0, 0);
        }
        // store weights: one dwordx4 per (rt,ct), plain cached store
        #pragma unroll
        for (int rt = 0; rt < 4; ++rt)
            #pragma unroll
            for (int ct = 0; ct < 4; ++ct)
                *(f32x4*)(dout + pixbase[rt] + m0 + ct * 16 + lg * 4) = acc[rt][ct];
        // fused einsum accumulation (rotated-o: o = (mc+ct+lg+r)%3)
        unsigned lutv[4];
#define ACCUM(QB)                                                              \
        _Pragma("unroll")                                                      \
        for (int ct = 0; ct < 4; ++ct) {                                       \
            *(uint4*)lutv = *(const uint4*)(sLUT + m0 + ct * 16 + lg * 4);     \
            _Pragma("unroll")                                                  \
            for (int r = 0; r < 4; ++r) {                                      \
                _Pragma("unroll")                                              \
                for (int rt = 0; rt < 4; ++rt) {                               \
                    float v = sX[lutv[r] + jl[rt]];                            \
                    racc[rt][((QB) + ct + r) % 3] =                            \
                        fmaf(acc[rt][ct][r], v, racc[rt][((QB) + ct + r) % 3]);\
                }                                                              \
            }                                                                  \
        }
        switch (mc % 3) {
            case 0: ACCUM(0); break;
            case 1: ACCUM(1); break;
            default: ACCUM(2); break;
        }
#undef ACCUM
    }

    // un-rotate (o = (q+lg3)%3), reduce across the 4 lg groups, stash
    #pragma unroll
    for (int rt = 0; rt < 4; ++rt) {
        float q0 = racc[rt][0], q1 = racc[rt][1], q2 = racc[rt][2];
        float a0 = (lg3 == 0) ? q0 : ((lg3 == 1) ? q2 : q1);
        float a1 = (lg3 == 0) ? q1 : ((lg3 == 1) ? q0 : q2);
        float a2 = (lg3 == 0) ? q2 : ((lg3 == 1) ? q1 : q0);
        a0 += __shfl_xor(a0, 16, 64); a0 += __shfl_xor(a0, 32, 64);
        a1 += __shfl_xor(a1, 16, 64); a1 += __shfl_xor(a1, 32, 64);
        a2 += __shfl_xor(a2, 16, 64); a2 += __shfl_xor(a2, 32, 64);
        if (l < 16) {
            float* so = sOut + (wid * 64 + rt * 16 + lm) * 3;
            so[0] = a0; so[1] = a1; so[2] = a2;
        }
    }
    __syncthreads();
    if (tid < 192) {
        float s = sOut[tid] + sOut[192 + tid] + sOut[384 + tid] + sOut[576 + tid];
        int pix = tid / 3, o = tid - 3 * pix;
        dout[bb * 3 * HWp + o * HWp + I * 128 + J0 + pix] = s;
    }
}

extern "C" void kernel_launch(void* const* d_in, const int* in_sizes, int n_in,
                              void* d_out, int out_size, void* d_ws, size_t ws_size,
                              hipStream_t stream) {
    const float* x0      = (const float*)d_in[0];
    const float* feature = (const float*)d_in[1];
    const float* pos     = (const float*)d_in[2];
    const float* w1      = (const float*)d_in[4];
    const float* b1      = (const float*)d_in[5];
    const float* w2      = (const float*)d_in[6];
    const float* b2      = (const float*)d_in[7];
    const float* f2w1_w  = (const float*)d_in[8];
    const float* f2w1_b  = (const float*)d_in[9];
    const float* f2w2_w  = (const float*)d_in[10];
    const float* f2w2_b  = (const float*)d_in[11];

    float* out = (float*)d_out;
    float* ws  = (float*)d_ws;
    float* f1  = ws + F1_OFF;
    float* fm  = ws + FM_OFF;
    short* wB2 = (short*)(ws + WB2_OFF);

    // 256 conv1 blocks + 1728 cvt blocks in one dispatch
    k13_conv1_cvt<<<256 + 1728, THREADS, 0, stream>>>(feature, w1, b1, f1, f2w2_w, wB2);
    k2_conv2_fm<<<(Bsz * 2 * HWp) / THREADS, THREADS, 0, stream>>>(f1, w2, b2, pos, fm);
    k4_gemm<<<Ntot / 64, THREADS, 0, stream>>>(fm, f2w1_w, f2w1_b, wB2, f2w2_b, x0, out);
}